// Round 1
// baseline (429.257 us; speedup 1.0000x reference)
//
#include <hip/hip_runtime.h>
#include <hip/hip_bf16.h>
#include <math.h>

#define NPTS 262144
#define TM   64      // points per block
#define NTHR 256     // 4 waves
// 32x32x16 MFMA layout. LDS strides for the transposed frag access:
// reads: lane (r = lane&31, h = lane>>5) reads point p = pt*32+r at k-off
// s*16 + h*8 -> 16B granule = (AS/8)*p + 2s + h. AS=264 (33 === 1 mod 8)
// gives granule = (p + 2s + h) mod 8: even 8 lanes/quad.
// writes: int2 at ch base 8q+4h for point r -> granule = (r + 4i + q) mod 8
// with h-halves pairing inside one granule: even 4/quad = BW-minimal.
// (R11 lesson: AS 264 vs 272 did NOT move SQ_LDS_BANK_CONFLICT for the old
// 16x16 pattern - counter is inherent to wave64 b128; 264 chosen because the
// 32x32 epilogue write pattern IS sensitive: 272 lands on even quads only.)
#define AS   264     // 33*16B rows
#define PS   80      // 10*16B rows

#define WS_SHORTS 593920   // prepacked weight image (bf16 elems)

typedef short  short8  __attribute__((ext_vector_type(8)));
typedef float  floatx16 __attribute__((ext_vector_type(16)));

__device__ __forceinline__ unsigned short f2b(float f) {  // RNE
  union { float f; unsigned int i; } v; v.f = f;
  return (unsigned short)((v.i + 0x7fffu + ((v.i >> 16) & 1u)) >> 16);
}
__device__ __forceinline__ float b2f(unsigned short u) {
  union { unsigned int i; float f; } v; v.i = ((unsigned int)u) << 16; return v.f;
}

// ---------------- weight prepack (32x32x16 frag layout) ----------------
// u = ct*512 + lane*8 + j  ->  W[n = ct*32 + (lane&31)][k = c*16 + (lane>>5)*8 + j]
struct PrepArgs {
  const float* src[10];
  unsigned short* ws;
  long long dst[10];
  int steps[10];
  int ksrc[10];
  int mode[10];   // 0: direct, 1: zero-pad >=ksrc, 2: L5 remap [base(256)|p(63)|pad]
  int nf32[10];   // 32-ch frags per k-step (8 for 256-out, 4 for r0)
};

__global__ __launch_bounds__(256) void prep_weights(PrepArgs P) {
  int jl = blockIdx.x, c = blockIdx.y;
  if (c >= P.steps[jl]) return;
  const int NF = P.nf32[jl], tot = NF * 512;
  const float* src = P.src[jl];
  const int Ks = P.ksrc[jl], mode = P.mode[jl];
  unsigned short* dst = P.ws + P.dst[jl] + (long long)c * tot;
  for (int u = threadIdx.x; u < tot; u += 256) {
    int j = u & 7, lane = (u >> 3) & 63, ct = u >> 9;
    int n  = ct * 32 + (lane & 31);
    int kp = c * 16 + ((lane >> 5) << 3) + j;
    int sc;
    if (mode == 0)      sc = kp;
    else if (mode == 1) sc = (kp < Ks) ? kp : -1;
    else                sc = (kp < 256) ? kp + 63 : (kp < Ks ? kp - 256 : -1);
    dst[u] = (sc >= 0) ? f2b(src[(long long)n * Ks + sc]) : (unsigned short)0;
  }
}

struct NerfArgs {
  const float* pts;
  const float* dirs;
  const unsigned short* ws;
  const float* bias[10];   // bb0..bb7, brm, br0
  const float* Wsig;
  const float* bsig;
  const float* Wr1;
  const float* br1;
  float* out;
};

// One layer via 32x32x16 MFMA: relu(act[64 x K] @ W^T + bias) -> act.
// TRANSPOSE TRICK preserved: D^T = (W-tile) x (act-tile); C/D layout (m74,
// verified): col = lane&31 = POINT within 32-pt tile, row = channel =
// (reg&3) + 8*(reg>>2) + 4*(lane>>5). Each reg-quad q -> 4 contiguous
// channels 8q+4h+{0..3} -> 8B ds_write_b64 epilogue (packed
// v_cvt_pk_bf16_f32, RNE = bit-identical to f2b).
// vs 16x16x32 (R11): HALF the MFMA instruction count (4/step of 32k FLOP vs
// 16/step of 16k over K=32), +15% MFMA pipe rate (m06: 2382 vs 2075 TF);
// identical ds_read/global-load counts and bytes, identical epilogue count.
// W-frags stream from global (L2-hot), 2-deep rotating register prefetch.
// acc starts at BIAS. All ds/global offsets = loop-invariant base +
// compile-time immediate. T5: s_setprio(1) around the MFMA cluster - 3
// blocks/CU sit at different layers -> scheduler role diversity (m191 regime).
template<int NFTOT, int NCT, int STEPS, int STEPS0, int LD0, int LD1>
__device__ __forceinline__ void gemm32(
    const unsigned short* wimg,
    const short* seg0, const short* seg1,
    const float* bias, short* dst, int tid)
{
  const int lane = tid & 63, wave = tid >> 6;
  const int r = lane & 31;          // A-row (channel) / B-col (point) in tile
  const int h = lane >> 5;          // k-half: k = s*16 + h*8 + j
  const int koff = h * 8;

  // acc = bias (broadcast across points): reg 4q+e -> channel 8q+4h+e
  floatx16 acc[2][NCT];
#pragma unroll
  for (int i = 0; i < NCT; ++i) {
    const float* bp = bias + (wave * NCT + i) * 32 + 4 * h;
    const float4 bq0 = *(const float4*)(bp);
    const float4 bq1 = *(const float4*)(bp + 8);
    const float4 bq2 = *(const float4*)(bp + 16);
    const float4 bq3 = *(const float4*)(bp + 24);
#pragma unroll
    for (int pt = 0; pt < 2; ++pt) {
      acc[pt][i][0]  = bq0.x; acc[pt][i][1]  = bq0.y; acc[pt][i][2]  = bq0.z; acc[pt][i][3]  = bq0.w;
      acc[pt][i][4]  = bq1.x; acc[pt][i][5]  = bq1.y; acc[pt][i][6]  = bq1.z; acc[pt][i][7]  = bq1.w;
      acc[pt][i][8]  = bq2.x; acc[pt][i][9]  = bq2.y; acc[pt][i][10] = bq2.z; acc[pt][i][11] = bq2.w;
      acc[pt][i][12] = bq3.x; acc[pt][i][13] = bq3.y; acc[pt][i][14] = bq3.z; acc[pt][i][15] = bq3.w;
    }
  }

  const unsigned short* wl = wimg + (size_t)(wave * NCT) * 512 + (size_t)lane * 8;
  const short* b0 = seg0 + (size_t)r * LD0 + koff;   // loop-invariant bases
  const short* b1 = seg1 + (size_t)r * LD1 + koff;

  // 2-deep rotating weight prefetch; all indices compile-time under unroll
  short8 wreg[3][NCT];
#pragma unroll
  for (int i = 0; i < NCT; ++i) wreg[0][i] = *(const short8*)(wl + i * 512);
  if (STEPS > 1) {
#pragma unroll
    for (int i = 0; i < NCT; ++i)
      wreg[1][i] = *(const short8*)(wl + (size_t)(NFTOT * 512) + i * 512);
  }

#pragma unroll
  for (int s = 0; s < STEPS; ++s) {
    if (s + 2 < STEPS) {
      const unsigned short* wn = wl + (size_t)(s + 2) * (NFTOT * 512);
#pragma unroll
      for (int i = 0; i < NCT; ++i)
        wreg[(s + 2) % 3][i] = *(const short8*)(wn + i * 512);
    }
    short8 b[2];
#pragma unroll
    for (int pt = 0; pt < 2; ++pt) {
      // act[point = pt*32 + r][s*16 + h*8 .. +7]; offset = compile-time imm
      if (s < STEPS0) b[pt] = *(const short8*)(b0 + pt * 32 * LD0 + s * 16);
      else            b[pt] = *(const short8*)(b1 + pt * 32 * LD1 + (s - STEPS0) * 16);
    }
    __builtin_amdgcn_s_setprio(1);
#pragma unroll
    for (int pt = 0; pt < 2; ++pt)
#pragma unroll
      for (int i = 0; i < NCT; ++i)
        acc[pt][i] = __builtin_amdgcn_mfma_f32_32x32x16_bf16(wreg[s % 3][i], b[pt], acc[pt][i], 0, 0, 0);
    __builtin_amdgcn_s_setprio(0);
  }
  __syncthreads();   // all waves' K-loop reads complete before in-place writes
  // epilogue: point = pt*32 + r, channel = (wave*NCT+i)*32 + 8q + 4h + e
  short* dstb = dst + (size_t)r * AS + wave * NCT * 32 + 4 * h;  // invariant base
#pragma unroll
  for (int i = 0; i < NCT; ++i) {
#pragma unroll
    for (int pt = 0; pt < 2; ++pt) {
#pragma unroll
      for (int q = 0; q < 4; ++q) {
        float v0 = fmaxf(acc[pt][i][4 * q + 0], 0.f);
        float v1 = fmaxf(acc[pt][i][4 * q + 1], 0.f);
        float v2 = fmaxf(acc[pt][i][4 * q + 2], 0.f);
        float v3 = fmaxf(acc[pt][i][4 * q + 3], 0.f);
        __hip_bfloat162 h01 = __float22bfloat162_rn(make_float2(v0, v1));
        __hip_bfloat162 h23 = __float22bfloat162_rn(make_float2(v2, v3));
        int2 pk;
        pk.x = *(const int*)&h01;
        pk.y = *(const int*)&h23;
        *(int2*)(dstb + (size_t)pt * 32 * AS + i * 32 + 8 * q) = pk;  // imm offset
      }
    }
  }
  __syncthreads();
}

__global__ __launch_bounds__(NTHR, 3)   // 3 blocks/CU (LDS 44032 B -> 3/CU)
void nerf_fused(NerfArgs A) {
  __shared__ alignas(16) short act[TM * AS];   // 33792 B
  __shared__ alignas(16) short pbuf[TM * PS];  // 10240 B  -> 44032 B total
  const int tid = threadIdx.x;
  const int lane = tid & 63, wave = tid >> 6;
  const size_t gbase = (size_t)blockIdx.x * TM;

  // pts embed, parallel over (row, dim): 192 threads; col 63 zero by the rest.
  // Trig: libm seed every 4 octaves + doubling (sin2a=2sc, cos2a=1-2s^2);
  // <=3 doublings per seed -> err ~5e-7, invisible vs bf16 storage; cuts
  // 20 libm chains -> 6 per thread.
  if (tid < 192) {
    int row = tid & 63, dim = tid >> 6;
    float x = A.pts[(gbase + row) * 3 + dim];
    short* pr = pbuf + row * PS;
    pr[dim] = (short)f2b(x);
    float s = 0.f, c = 0.f, fr = 1.f;
#pragma unroll
    for (int q = 0; q < 10; ++q) {
      if ((q & 3) == 0) { s = sinf(x * fr); c = cosf(x * fr); }
      pr[3 + q * 6 + dim]     = (short)f2b(s);
      pr[3 + q * 6 + 3 + dim] = (short)f2b(c);
      float ns = 2.f * s * c;
      float nc = 1.f - 2.f * s * s;
      s = ns; c = nc;
      fr *= 2.f;
    }
  } else {
    pbuf[(tid - 192) * PS + 63] = 0;
  }
  __syncthreads();

  const short* actp = act;
  short*       actw = act;
  const short* pbp  = pbuf;
  const unsigned short* ws = A.ws;

  gemm32<8, 2,  4,  4, PS, AS>(ws + 0,      pbp,  actp, A.bias[0], actw, tid);
  gemm32<8, 2, 16, 16, AS, AS>(ws + 16384,  actp, actp, A.bias[1], actw, tid);
  gemm32<8, 2, 16, 16, AS, AS>(ws + 81920,  actp, actp, A.bias[2], actw, tid);
  gemm32<8, 2, 16, 16, AS, AS>(ws + 147456, actp, actp, A.bias[3], actw, tid);
  gemm32<8, 2, 16, 16, AS, AS>(ws + 212992, actp, actp, A.bias[4], actw, tid);
  gemm32<8, 2, 20, 16, AS, PS>(ws + 278528, actp, pbp,  A.bias[5], actw, tid);

  // p dead: dirs embed into pbuf (cols 0..26; 27..31 zero) + d output.
  // d written as 27 CONTIGUOUS f32 per thread (clean WRITE=31MB; scattered
  // per-dim stores caused partial-line RMW thrash). Trig: exact seed + 3
  // doublings (err <1e-6 on the exactly-compared d output).
  if (tid >= 64 && tid < 128) {
    int row = tid - 64;
    size_t g = gbase + row;
    float x0 = A.dirs[g * 3 + 0];
    float x1 = A.dirs[g * 3 + 1];
    float x2 = A.dirs[g * 3 + 2];
    float vals[27];
    vals[0] = x0; vals[1] = x1; vals[2] = x2;
    float sx = sinf(x0), cx = cosf(x0);
    float sy = sinf(x1), cy = cosf(x1);
    float sz = sinf(x2), cz = cosf(x2);
#pragma unroll
    for (int q = 0; q < 4; ++q) {
      vals[3 + q * 6 + 0] = sx;
      vals[3 + q * 6 + 1] = sy;
      vals[3 + q * 6 + 2] = sz;
      vals[3 + q * 6 + 3] = cx;
      vals[3 + q * 6 + 4] = cy;
      vals[3 + q * 6 + 5] = cz;
      float nsx = 2.f * sx * cx, ncx = 1.f - 2.f * sx * sx;
      float nsy = 2.f * sy * cy, ncy = 1.f - 2.f * sy * sy;
      float nsz = 2.f * sz * cz, ncz = 1.f - 2.f * sz * sz;
      sx = nsx; cx = ncx; sy = nsy; cy = ncy; sz = nsz; cz = ncz;
    }
    short* dr = pbuf + row * PS;
    float* og = A.out + (size_t)4 * NPTS + g * 27;
    for (int j = 0; j < 27; ++j) {
      dr[j] = (short)f2b(vals[j]);
      og[j] = vals[j];
    }
    for (int j = 27; j < 32; ++j) dr[j] = 0;
  }
  // no barrier needed: L6's epilogue barriers order these writes before r0's reads

  gemm32<8, 2, 16, 16, AS, AS>(ws + 360448, actp, actp, A.bias[6], actw, tid);
  gemm32<8, 2, 16, 16, AS, AS>(ws + 425984, actp, actp, A.bias[7], actw, tid);

  // sigma head (SIGMA_MUL=0 -> passthrough): point = wave*16+(lane&15), k-quarter = lane>>4
  {
    int p = wave * 16 + (lane & 15);
    int q = lane >> 4;
    float s = 0.f;
    for (int c8 = 0; c8 < 8; ++c8) {
      int k0 = q * 64 + c8 * 8;
      short8 v = *(const short8*)(act + p * AS + k0);
      const float4 w0 = *(const float4*)(A.Wsig + k0);
      const float4 w1 = *(const float4*)(A.Wsig + k0 + 4);
      s += b2f((unsigned short)v[0]) * w0.x + b2f((unsigned short)v[1]) * w0.y
         + b2f((unsigned short)v[2]) * w0.z + b2f((unsigned short)v[3]) * w0.w
         + b2f((unsigned short)v[4]) * w1.x + b2f((unsigned short)v[5]) * w1.y
         + b2f((unsigned short)v[6]) * w1.z + b2f((unsigned short)v[7]) * w1.w;
    }
    s += __shfl_xor(s, 16);
    s += __shfl_xor(s, 32);
    if (q == 0) A.out[(size_t)3 * NPTS + gbase + p] = s + A.bsig[0];
  }
  // sigma reads of act are ordered before rm's in-place writes by rm's pre-epilogue barrier

  gemm32<8, 2, 16, 16, AS, AS>(ws + 491520, actp, actp, A.bias[8], actw, tid);
  gemm32<4, 1, 18, 16, AS, PS>(ws + 557056, actp, pbp,  A.bias[9], actw, tid);

  // rgb head: sigmoid(fea[128] @ Wr1^T + br1): point = wave*16+(lane&15), k-quarter = lane>>4
  {
    int p = wave * 16 + (lane & 15);
    int q = lane >> 4;
    float s0 = 0.f, s1 = 0.f, s2 = 0.f;
    for (int c8 = 0; c8 < 4; ++c8) {
      int k0 = q * 32 + c8 * 8;
      short8 v = *(const short8*)(act + p * AS + k0);
#pragma unroll
      for (int j = 0; j < 8; ++j) {
        float fv = b2f((unsigned short)v[j]);
        s0 += fv * A.Wr1[k0 + j];
        s1 += fv * A.Wr1[128 + k0 + j];
        s2 += fv * A.Wr1[256 + k0 + j];
      }
    }
    s0 += __shfl_xor(s0, 16); s0 += __shfl_xor(s0, 32);
    s1 += __shfl_xor(s1, 16); s1 += __shfl_xor(s1, 32);
    s2 += __shfl_xor(s2, 16); s2 += __shfl_xor(s2, 32);
    if (q == 0) {
      size_t g = gbase + p;
      A.out[g * 3 + 0] = 1.f / (1.f + expf(-(s0 + A.br1[0])));
      A.out[g * 3 + 1] = 1.f / (1.f + expf(-(s1 + A.br1[1])));
      A.out[g * 3 + 2] = 1.f / (1.f + expf(-(s2 + A.br1[2])));
    }
  }
}

extern "C" void kernel_launch(void* const* d_in, const int* in_sizes, int n_in,
                              void* d_out, int out_size, void* d_ws, size_t ws_size,
                              hipStream_t stream) {
  // input order: pts, dirs, (Wb_i, bb_i)*8, Wsig, bsig, Wrm, brm, Wr0, br0, Wr1, br1
  PrepArgs pp;
  const int       widx[10]  = {2, 4, 6, 8, 10, 12, 14, 16, 20, 22};
  const long long doffs[10] = {0, 16384, 81920, 147456, 212992, 278528,
                               360448, 425984, 491520, 557056};
  const int stv[10] = {4, 16, 16, 16, 16, 20, 16, 16, 16, 18};
  const int ksv[10] = {63, 256, 256, 256, 256, 319, 256, 256, 256, 283};
  const int mdv[10] = {1, 0, 0, 0, 0, 2, 0, 0, 0, 1};
  const int nfv[10] = {8, 8, 8, 8, 8, 8, 8, 8, 8, 4};
  pp.ws = (unsigned short*)d_ws;   // needs WS_SHORTS*2 = 1.19 MB (verified fits)
  for (int j = 0; j < 10; ++j) {
    pp.src[j] = (const float*)d_in[widx[j]];
    pp.dst[j] = doffs[j]; pp.steps[j] = stv[j]; pp.ksrc[j] = ksv[j];
    pp.mode[j] = mdv[j]; pp.nf32[j] = nfv[j];
  }
  prep_weights<<<dim3(10, 20), dim3(256), 0, stream>>>(pp);

  NerfArgs na;
  na.pts  = (const float*)d_in[0];
  na.dirs = (const float*)d_in[1];
  na.ws   = (const unsigned short*)d_ws;
  for (int i = 0; i < 8; ++i) na.bias[i] = (const float*)d_in[3 + 2 * i];
  na.bias[8] = (const float*)d_in[21];  // brm
  na.bias[9] = (const float*)d_in[23];  // br0
  na.Wsig = (const float*)d_in[18];
  na.bsig = (const float*)d_in[19];
  na.Wr1  = (const float*)d_in[24];
  na.br1  = (const float*)d_in[25];
  na.out  = (float*)d_out;
  nerf_fused<<<dim3(NPTS / TM), dim3(NTHR), 0, stream>>>(na);
}

// Round 2
// 398.864 us; speedup vs baseline: 1.0762x; 1.0762x over previous
//
#include <hip/hip_runtime.h>
#include <hip/hip_bf16.h>
#include <math.h>

#define NPTS 262144
#define TM   64      // points per block
#define NTHR 256     // 4 waves
// LDS strides chosen for the TRANSPOSED frag access (lane = g*16+p reads
// row p at k-offset g*8): bank-quad = p*(AS/8) + g (mod 32). AS/8 must be
// ===2 (mod 32) so 2p+g covers each bank exactly twice (2-way = free, m136).
// R9/R10's AS=264 (33 units === 1) gave p+g -> 4-way conflicts = 3.25e7
// counter = ~16% of cycles.
// R12 LESSON (32x32x16 experiment, 310->342us REGRESSION): halving MFMA
// inst count with v_mfma_f32_32x32x16_bf16 LOWERED both MfmaUtil (46->43)
// and VALUBusy (39->29) yet slowed the kernel: only 4 independent acc
// chains/K-step (vs 16 here) -> ~32 cyc of issue per dependency round can't
// hide MFMA+LDS latency -> per-step stalls. 16 independent 16x16 chains
// (~77 cyc issue/round) DO hide it. Keep 16x16x32.
#define AS   272     // 34*16B rows (34 === 2 mod 32)
#define PS   80      // 10*16B rows (10 === 2 mod 32)

#define WS_SHORTS 593920   // prepacked weight image (bf16 elems)

typedef short  short8  __attribute__((ext_vector_type(8)));
typedef float  floatx4 __attribute__((ext_vector_type(4)));

__device__ __forceinline__ unsigned short f2b(float f) {  // RNE
  union { float f; unsigned int i; } v; v.f = f;
  return (unsigned short)((v.i + 0x7fffu + ((v.i >> 16) & 1u)) >> 16);
}
__device__ __forceinline__ float b2f(unsigned short u) {
  union { unsigned int i; float f; } v; v.i = ((unsigned int)u) << 16; return v.f;
}

// ---------------- weight prepack (identical image since R5) ----------------
// u = nf*512 + lane*8 + j  ->  W[n = nf*16 + (lane&15)][k = c*32 + (lane>>4)*8 + j]
struct PrepArgs {
  const float* src[10];
  unsigned short* ws;
  long long dst[10];
  int steps[10];
  int ksrc[10];
  int mode[10];   // 0: direct, 1: zero-pad >=ksrc, 2: L5 remap [base(256)|p(63)|pad]
  int nf16[10];
};

__global__ __launch_bounds__(256) void prep_weights(PrepArgs P) {
  int jl = blockIdx.x, c = blockIdx.y;
  if (c >= P.steps[jl]) return;
  const int NF = P.nf16[jl], tot = NF * 512;
  const float* src = P.src[jl];
  const int Ks = P.ksrc[jl], mode = P.mode[jl];
  unsigned short* dst = P.ws + P.dst[jl] + (long long)c * tot;
  for (int u = threadIdx.x; u < tot; u += 256) {
    int j = u & 7, lane = (u >> 3) & 63, nf = u >> 9;
    int n  = nf * 16 + (lane & 15);
    int kp = c * 32 + ((lane >> 4) << 3) + j;
    int sc;
    if (mode == 0)      sc = kp;
    else if (mode == 1) sc = (kp < Ks) ? kp : -1;
    else                sc = (kp < 256) ? kp + 63 : (kp < Ks ? kp - 256 : -1);
    dst[u] = (sc >= 0) ? f2b(src[(long long)n * Ks + sc]) : (unsigned short)0;
  }
}

struct NerfArgs {
  const float* pts;
  const float* dirs;
  const unsigned short* ws;
  const float* bias[10];   // bb0..bb7, brm, br0
  const float* Wsig;
  const float* bsig;
  const float* Wr1;
  const float* br1;
  float* out;
};

// One layer: relu(act[64 x K] @ W^T + bias) -> act (in-place safe).
// TRANSPOSE TRICK: D^T = (W-tile) x (act-tile); each lane gets 4 contiguous
// channels for point col=lane&15 -> 8B ds_write_b64 epilogue (packed
// v_cvt_pk_bf16_f32 via __float22bfloat162_rn, RNE = bit-identical to f2b).
// W-frags stream from global (L2-hot prepacked image), 2-deep rotating
// register prefetch (R10: neutral vs 1-deep, kept). acc starts at BIAS.
// act-frags from PADDED LDS: every ds address = loop-invariant base +
// compile-time immediate (runtime swizzle math cost 42% VALUBusy in R8).
// T5: s_setprio(1) around the MFMA cluster - 3 blocks/CU sit at different
// layers -> scheduler role diversity (m191 regime, not lockstep-GEMM m190).
// REGISTER BUDGET (gfx950 unified VGPR/AGPR): 64 AGPR acc + 48 wreg + ~35
// misc ~= 147 < 170 cap at min-waves 3. min-waves 4 (128 cap) spills 1.3GB
// (R6); runtime layer params spill ~250MB (R7). FETCH_SIZE >> 10MB = spill.
template<int NFTOT, int NFW, int STEPS, int STEPS0, int LD0, int LD1>
__device__ __forceinline__ void gemm_g(
    const unsigned short* wimg,
    const short* seg0, const short* seg1,
    const float* bias, short* dst, int tid)
{
  const int lane = tid & 63, wave = tid >> 6;
  const int prow = lane & 15;
  const int r4   = (lane >> 4) * 4;
  const int koff = (lane >> 4) * 8;

  // acc = bias (broadcast across points); bv dead after this block
  floatx4 acc[4][NFW];
  {
    float4 bv[NFW];
#pragma unroll
    for (int i = 0; i < NFW; ++i)
      bv[i] = *(const float4*)(bias + (wave * NFW + i) * 16 + r4);
#pragma unroll
    for (int mf = 0; mf < 4; ++mf)
#pragma unroll
      for (int i = 0; i < NFW; ++i) {
        acc[mf][i][0] = bv[i].x; acc[mf][i][1] = bv[i].y;
        acc[mf][i][2] = bv[i].z; acc[mf][i][3] = bv[i].w;
      }
  }

  const unsigned short* wl = wimg + (size_t)(wave * NFW) * 512 + (size_t)lane * 8;
  const short* b0 = seg0 + (size_t)prow * LD0 + koff;   // loop-invariant bases
  const short* b1 = seg1 + (size_t)prow * LD1 + koff;

  // 2-deep rotating weight prefetch; all indices compile-time under unroll
  short8 wreg[3][NFW];
#pragma unroll
  for (int i = 0; i < NFW; ++i) wreg[0][i] = *(const short8*)(wl + i * 512);
  if (STEPS > 1) {
#pragma unroll
    for (int i = 0; i < NFW; ++i)
      wreg[1][i] = *(const short8*)(wl + (size_t)(NFTOT * 512) + i * 512);
  }

#pragma unroll
  for (int s = 0; s < STEPS; ++s) {
    if (s + 2 < STEPS) {
      const unsigned short* wn = wl + (size_t)(s + 2) * (NFTOT * 512);
#pragma unroll
      for (int i = 0; i < NFW; ++i)
        wreg[(s + 2) % 3][i] = *(const short8*)(wn + i * 512);
    }
    short8 b[4];
#pragma unroll
    for (int mf = 0; mf < 4; ++mf) {
      // act[point = mf*16+prow][kl+koff .. +7]; offset is a compile-time imm
      if (s < STEPS0) b[mf] = *(const short8*)(b0 + mf * 16 * LD0 + s * 32);
      else            b[mf] = *(const short8*)(b1 + mf * 16 * LD1 + (s - STEPS0) * 32);
    }
    __builtin_amdgcn_s_setprio(1);
#pragma unroll
    for (int mf = 0; mf < 4; ++mf)
#pragma unroll
      for (int i = 0; i < NFW; ++i)
        acc[mf][i] = __builtin_amdgcn_mfma_f32_16x16x32_bf16(wreg[s % 3][i], b[mf], acc[mf][i], 0, 0, 0);
    __builtin_amdgcn_s_setprio(0);
  }
  __syncthreads();   // all waves' K-loop reads complete before in-place writes
  // D^T C/D layout: channel n = (wave*NFW+i)*16 + r4 + r, point = mf*16 + prow
  short* dstb = dst + (size_t)prow * AS + wave * NFW * 16 + r4;  // loop-invariant base
#pragma unroll
  for (int i = 0; i < NFW; ++i) {
#pragma unroll
    for (int mf = 0; mf < 4; ++mf) {
      float v0 = fmaxf(acc[mf][i][0], 0.f);
      float v1 = fmaxf(acc[mf][i][1], 0.f);
      float v2 = fmaxf(acc[mf][i][2], 0.f);
      float v3 = fmaxf(acc[mf][i][3], 0.f);
      __hip_bfloat162 h01 = __float22bfloat162_rn(make_float2(v0, v1));
      __hip_bfloat162 h23 = __float22bfloat162_rn(make_float2(v2, v3));
      int2 pk;
      pk.x = *(const int*)&h01;
      pk.y = *(const int*)&h23;
      *(int2*)(dstb + mf * 16 * AS + i * 16) = pk;   // compile-time imm offset
    }
  }
  __syncthreads();
}

__global__ __launch_bounds__(NTHR, 3)   // 3 blocks/CU: see register-budget note
void nerf_fused(NerfArgs A) {
  __shared__ alignas(16) short act[TM * AS];   // 34816 B
  __shared__ alignas(16) short pbuf[TM * PS];  // 10240 B  -> 45056 B total
  const int tid = threadIdx.x;
  const int lane = tid & 63, wave = tid >> 6;
  const size_t gbase = (size_t)blockIdx.x * TM;

  // pts embed, parallel over (row, dim): 192 threads; col 63 zero by the rest.
  // Trig: libm seed every 4 octaves + doubling (sin2a=2sc, cos2a=1-2s^2);
  // <=3 doublings per seed -> err ~5e-7, invisible vs bf16 storage; cuts
  // 20 libm chains -> 6 per thread. (R12: absmax unchanged at 0.0039.)
  if (tid < 192) {
    int row = tid & 63, dim = tid >> 6;
    float x = A.pts[(gbase + row) * 3 + dim];
    short* pr = pbuf + row * PS;
    pr[dim] = (short)f2b(x);
    float s = 0.f, c = 0.f, fr = 1.f;
#pragma unroll
    for (int q = 0; q < 10; ++q) {
      if ((q & 3) == 0) { s = sinf(x * fr); c = cosf(x * fr); }
      pr[3 + q * 6 + dim]     = (short)f2b(s);
      pr[3 + q * 6 + 3 + dim] = (short)f2b(c);
      float ns = 2.f * s * c;
      float nc = 1.f - 2.f * s * s;
      s = ns; c = nc;
      fr *= 2.f;
    }
  } else {
    pbuf[(tid - 192) * PS + 63] = 0;
  }
  __syncthreads();

  const short* actp = act;
  short*       actw = act;
  const short* pbp  = pbuf;
  const unsigned short* ws = A.ws;

  gemm_g<16, 4,  2, 2, PS, AS>(ws + 0,      pbp,  actp, A.bias[0], actw, tid);
  gemm_g<16, 4,  8, 8, AS, AS>(ws + 16384,  actp, actp, A.bias[1], actw, tid);
  gemm_g<16, 4,  8, 8, AS, AS>(ws + 81920,  actp, actp, A.bias[2], actw, tid);
  gemm_g<16, 4,  8, 8, AS, AS>(ws + 147456, actp, actp, A.bias[3], actw, tid);
  gemm_g<16, 4,  8, 8, AS, AS>(ws + 212992, actp, actp, A.bias[4], actw, tid);
  gemm_g<16, 4, 10, 8, AS, PS>(ws + 278528, actp, pbp,  A.bias[5], actw, tid);

  // p dead: dirs embed into pbuf (cols 0..26; 27..31 zero) + d output.
  // d written as 27 CONTIGUOUS f32 per thread (measured clean WRITE=31MB).
  // Scattered per-dim stores (R6-R8) caused partial-line RMW thrash under L2
  // pressure: WRITE 269MB / FETCH +100MB. Keep contiguous.
  // Trig: exact seed + 3 doublings (err <1e-6 on the exactly-compared d).
  if (tid >= 64 && tid < 128) {
    int row = tid - 64;
    size_t g = gbase + row;
    float x0 = A.dirs[g * 3 + 0];
    float x1 = A.dirs[g * 3 + 1];
    float x2 = A.dirs[g * 3 + 2];
    float vals[27];
    vals[0] = x0; vals[1] = x1; vals[2] = x2;
    float sx = sinf(x0), cx = cosf(x0);
    float sy = sinf(x1), cy = cosf(x1);
    float sz = sinf(x2), cz = cosf(x2);
#pragma unroll
    for (int q = 0; q < 4; ++q) {
      vals[3 + q * 6 + 0] = sx;
      vals[3 + q * 6 + 1] = sy;
      vals[3 + q * 6 + 2] = sz;
      vals[3 + q * 6 + 3] = cx;
      vals[3 + q * 6 + 4] = cy;
      vals[3 + q * 6 + 5] = cz;
      float nsx = 2.f * sx * cx, ncx = 1.f - 2.f * sx * sx;
      float nsy = 2.f * sy * cy, ncy = 1.f - 2.f * sy * sy;
      float nsz = 2.f * sz * cz, ncz = 1.f - 2.f * sz * sz;
      sx = nsx; cx = ncx; sy = nsy; cy = ncy; sz = nsz; cz = ncz;
    }
    short* dr = pbuf + row * PS;
    float* og = A.out + (size_t)4 * NPTS + g * 27;
    for (int j = 0; j < 27; ++j) {
      dr[j] = (short)f2b(vals[j]);
      og[j] = vals[j];
    }
    for (int j = 27; j < 32; ++j) dr[j] = 0;
  }
  // no barrier needed: L6's epilogue barriers order these writes before r0's reads

  gemm_g<16, 4,  8, 8, AS, AS>(ws + 360448, actp, actp, A.bias[6], actw, tid);
  gemm_g<16, 4,  8, 8, AS, AS>(ws + 425984, actp, actp, A.bias[7], actw, tid);

  // sigma head (SIGMA_MUL=0 -> passthrough): point = wave*16+(lane&15), k-quarter = lane>>4
  {
    int p = wave * 16 + (lane & 15);
    int q = lane >> 4;
    float s = 0.f;
    for (int c8 = 0; c8 < 8; ++c8) {
      int k0 = q * 64 + c8 * 8;
      short8 v = *(const short8*)(act + p * AS + k0);
      const float4 w0 = *(const float4*)(A.Wsig + k0);
      const float4 w1 = *(const float4*)(A.Wsig + k0 + 4);
      s += b2f((unsigned short)v[0]) * w0.x + b2f((unsigned short)v[1]) * w0.y
         + b2f((unsigned short)v[2]) * w0.z + b2f((unsigned short)v[3]) * w0.w
         + b2f((unsigned short)v[4]) * w1.x + b2f((unsigned short)v[5]) * w1.y
         + b2f((unsigned short)v[6]) * w1.z + b2f((unsigned short)v[7]) * w1.w;
    }
    s += __shfl_xor(s, 16);
    s += __shfl_xor(s, 32);
    if (q == 0) A.out[(size_t)3 * NPTS + gbase + p] = s + A.bsig[0];
  }
  // sigma reads of act are ordered before rm's in-place writes by rm's pre-epilogue barrier

  gemm_g<16, 4,  8, 8, AS, AS>(ws + 491520, actp, actp, A.bias[8], actw, tid);
  gemm_g< 8, 2,  9, 8, AS, PS>(ws + 557056, actp, pbp,  A.bias[9], actw, tid);

  // rgb head: sigmoid(fea[128] @ Wr1^T + br1): point = wave*16+(lane&15), k-quarter = lane>>4
  {
    int p = wave * 16 + (lane & 15);
    int q = lane >> 4;
    float s0 = 0.f, s1 = 0.f, s2 = 0.f;
    for (int c8 = 0; c8 < 4; ++c8) {
      int k0 = q * 32 + c8 * 8;
      short8 v = *(const short8*)(act + p * AS + k0);
#pragma unroll
      for (int j = 0; j < 8; ++j) {
        float fv = b2f((unsigned short)v[j]);
        s0 += fv * A.Wr1[k0 + j];
        s1 += fv * A.Wr1[128 + k0 + j];
        s2 += fv * A.Wr1[256 + k0 + j];
      }
    }
    s0 += __shfl_xor(s0, 16); s0 += __shfl_xor(s0, 32);
    s1 += __shfl_xor(s1, 16); s1 += __shfl_xor(s1, 32);
    s2 += __shfl_xor(s2, 16); s2 += __shfl_xor(s2, 32);
    if (q == 0) {
      size_t g = gbase + p;
      A.out[g * 3 + 0] = 1.f / (1.f + expf(-(s0 + A.br1[0])));
      A.out[g * 3 + 1] = 1.f / (1.f + expf(-(s1 + A.br1[1])));
      A.out[g * 3 + 2] = 1.f / (1.f + expf(-(s2 + A.br1[2])));
    }
  }
}

extern "C" void kernel_launch(void* const* d_in, const int* in_sizes, int n_in,
                              void* d_out, int out_size, void* d_ws, size_t ws_size,
                              hipStream_t stream) {
  // input order: pts, dirs, (Wb_i, bb_i)*8, Wsig, bsig, Wrm, brm, Wr0, br0, Wr1, br1
  PrepArgs pp;
  const int       widx[10]  = {2, 4, 6, 8, 10, 12, 14, 16, 20, 22};
  const long long doffs[10] = {0, 16384, 81920, 147456, 212992, 278528,
                               360448, 425984, 491520, 557056};
  const int stv[10] = {2, 8, 8, 8, 8, 10, 8, 8, 8, 9};
  const int ksv[10] = {63, 256, 256, 256, 256, 319, 256, 256, 256, 283};
  const int mdv[10] = {1, 0, 0, 0, 0, 2, 0, 0, 0, 1};
  const int nfv[10] = {16, 16, 16, 16, 16, 16, 16, 16, 16, 8};
  pp.ws = (unsigned short*)d_ws;   // needs WS_SHORTS*2 = 1.19 MB (verified fits)
  for (int j = 0; j < 10; ++j) {
    pp.src[j] = (const float*)d_in[widx[j]];
    pp.dst[j] = doffs[j]; pp.steps[j] = stv[j]; pp.ksrc[j] = ksv[j];
    pp.mode[j] = mdv[j]; pp.nf16[j] = nfv[j];
  }
  prep_weights<<<dim3(10, 10), dim3(256), 0, stream>>>(pp);

  NerfArgs na;
  na.pts  = (const float*)d_in[0];
  na.dirs = (const float*)d_in[1];
  na.ws   = (const unsigned short*)d_ws;
  for (int i = 0; i < 8; ++i) na.bias[i] = (const float*)d_in[3 + 2 * i];
  na.bias[8] = (const float*)d_in[21];  // brm
  na.bias[9] = (const float*)d_in[23];  // br0
  na.Wsig = (const float*)d_in[18];
  na.bsig = (const float*)d_in[19];
  na.Wr1  = (const float*)d_in[24];
  na.br1  = (const float*)d_in[25];
  na.out  = (float*)d_out;
  nerf_fused<<<dim3(NPTS / TM), dim3(NTHR), 0, stream>>>(na);
}